// Round 12
// baseline (8140.958 us; speedup 1.0000x reference)
//
#include <hip/hip_runtime.h>
#include <stdint.h>
#include <math.h>

#define BB 8
#define NN 16384
#define CC 13
#define GG 512
#define KK 32

#define NEIGH_ELEMS (BB*GG*KK*CC)   // 1,703,936

#define SHARDS 8
#define SHARD_PTS (NN / SHARDS)     // 2048
#define FPS_THREADS 512
#define PPT (SHARD_PTS / FPS_THREADS)  // 4 points per thread

// ---------------------------------------------------------------------------
// Pack: x[B,N,13] (fp32) -> f32 SoA planes px,py,pz (channels 4..6).
// ---------------------------------------------------------------------------
__global__ void pack_kernel(const float* __restrict__ x,
                            float* __restrict__ px, float* __restrict__ py,
                            float* __restrict__ pz) {
    int i = blockIdx.x * blockDim.x + threadIdx.x;
    if (i >= BB * NN) return;
    const float* p = x + (size_t)i * CC + 4;
    px[i] = p[0]; py[i] = p[1]; pz[i] = p[2];
}

// ---------------------------------------------------------------------------
// Zero the handshake slots (key+cnt). MUST run before fps every launch:
// the harness poisons d_ws with 0xAA, which would pre-satisfy the spin.
// ---------------------------------------------------------------------------
__global__ void init_sync_kernel(unsigned long long* __restrict__ key,
                                 unsigned int* __restrict__ cnt) {
    int i = blockIdx.x * blockDim.x + threadIdx.x;
    if (i < BB * GG) { key[i] = 0ull; cnt[i] = 0u; }
}

// ---------------------------------------------------------------------------
// FPS v7 — SHARDED: 8 blocks per batch (64 total), each owns 2048 points
// (4/thread: ~45 VGPRs, nothing can spill). Per step: shard argmax
// (butterfly + parity LDS partials, one barrier), then a device-scope
// handshake: atomicMax of key = (bits(bv)<<32)|(0xFFFFFFFF-bp)  [bv>=0 so
// float bits are order-isomorphic; low word = lowest-index tie-break, exact
// top-1 semantics], release-counter bump, acquire-spin until all 8 shards
// posted. Winner decoded locally; keys unique -> deterministic.
// R6..R11 post-mortem: single-block FPS is issue/latency-bound on 8 CUs at
// ~2.3-2.9us/step regardless of register strategy; this spreads the step
// across 64 CUs. Distance math verbatim from R6 (bit-exact vs golden).
// Shards of a batch share an XCD via blockIdx swizzle (perf-only).
// ---------------------------------------------------------------------------
__global__ __launch_bounds__(FPS_THREADS)
void fps_kernel(const float* __restrict__ px,
                const float* __restrict__ py,
                const float* __restrict__ pz,
                float* __restrict__ centers,
                unsigned long long* __restrict__ key,
                unsigned int* __restrict__ cnt) {
    const int b = blockIdx.x & 7;        // batch  (same XCD for all its shards)
    const int s = blockIdx.x >> 3;       // shard
    const int t = threadIdx.x;
    const float* PX = px + b * NN;
    const float* PY = py + b * NN;
    const float* PZ = pz + b * NN;
    unsigned long long* KEY = key + (size_t)b * GG;
    unsigned int*       CNT = cnt + (size_t)b * GG;

    const int base = s * SHARD_PTS + t;  // + i*512
    float X[PPT], Y[PPT], Z[PPT], MD[PPT];
#pragma unroll
    for (int i = 0; i < PPT; ++i) {
        int pos = base + (i << 9);
        X[i] = PX[pos]; Y[i] = PY[pos]; Z[i] = PZ[pos];
        MD[i] = 1e10f;   // init_d = 10000000000.0
    }

    __shared__ float s_v[2][8];
    __shared__ int   s_p[2][8];

    // g = 0: center is point 0
    if (s == 0 && t == 0) {
        float* oc = centers + (size_t)b * GG * 3;
        oc[0] = PX[0]; oc[1] = PY[0]; oc[2] = PZ[0];
    }
    float lx = PX[0], ly = PY[0], lz = PZ[0];

    for (int g = 1; g < GG; ++g) {
        float bv = -1.0f;
        int bp = 0x7fffffff;
#pragma unroll
        for (int i = 0; i < PPT; ++i) {
            float e0 = __fsub_rn(X[i], lx);
            float e1 = __fsub_rn(Y[i], ly);
            float e2 = __fsub_rn(Z[i], lz);
            float d  = __fadd_rn(__fadd_rn(__fmul_rn(e0, e0), __fmul_rn(e1, e1)),
                                 __fmul_rn(e2, e2));
            float m = fminf(MD[i], d);   // np.minimum
            MD[i] = m;
            // ascending-index scan + strict '>' keeps lowest index on ties
            if (m > bv) { bv = m; bp = base + (i << 9); }
        }
        // wave(64) butterfly argmax, tie -> lower index
#pragma unroll
        for (int off = 32; off >= 1; off >>= 1) {
            float ov = __shfl_xor(bv, off);
            int   op = __shfl_xor(bp, off);
            if (ov > bv || (ov == bv && op < bp)) { bv = ov; bp = op; }
        }
        int par = g & 1;
        int w = t >> 6;
        if ((t & 63) == 0) { s_v[par][w] = bv; s_p[par][w] = bp; }
        __syncthreads();
        // redundant scan of 8 partials by every thread
        float wv = s_v[par][0]; int wi = s_p[par][0];
#pragma unroll
        for (int q = 1; q < 8; ++q) {
            float qv = s_v[par][q]; int qp = s_p[par][q];
            if (qv > wv || (qv == wv && qp < wi)) { wv = qv; wi = qp; }
        }
        // publish shard result; last word wins via atomicMax on packed key
        if (t == 0) {
            unsigned long long k =
                ((unsigned long long)__float_as_uint(wv) << 32) |
                (unsigned long long)(0xFFFFFFFFu - (unsigned int)wi);
            atomicMax(&KEY[g], k);   // device scope
            __hip_atomic_fetch_add(&CNT[g], 1u, __ATOMIC_RELEASE,
                                   __HIP_MEMORY_SCOPE_AGENT);
        }
        // all threads spin until all shards posted (acquire pairs w/ release)
        while (__hip_atomic_load(&CNT[g], __ATOMIC_ACQUIRE,
                                 __HIP_MEMORY_SCOPE_AGENT) < SHARDS) { }
        unsigned long long wk = __hip_atomic_load(&KEY[g], __ATOMIC_ACQUIRE,
                                                  __HIP_MEMORY_SCOPE_AGENT);
        int wp = (int)(0xFFFFFFFFu - (unsigned int)(wk & 0xFFFFFFFFull));
        // scalar broadcast load of winner coords (uniform index)
        int swp = __builtin_amdgcn_readfirstlane(wp);
        lx = PX[swp]; ly = PY[swp]; lz = PZ[swp];
        if (s == 0 && t == 0) {
            float* oc = centers + ((size_t)b * GG + g) * 3;
            oc[0] = lx; oc[1] = ly; oc[2] = lz;
        }
        // no second barrier: parity buffer isolates next round's writes
    }
}

// ---------------------------------------------------------------------------
// KNN v2 + gather (unchanged from R8): one 256-thread block per center,
// 64 pts/thread, top-2 cache + rare global rescan; XCD swizzle keeps each
// batch's SoA L2-resident on one XCD. d2 math bit-exact vs golden.
// ---------------------------------------------------------------------------
__global__ __launch_bounds__(256, 8) void knn_kernel(const float* __restrict__ px,
                                                     const float* __restrict__ py,
                                                     const float* __restrict__ pz,
                                                     const float* __restrict__ x,
                                                     const float* __restrict__ centers,
                                                     float* __restrict__ out) {
    const int blk = blockIdx.x;
    const int bg  = ((blk & 7) << 9) | (blk >> 3);   // batch = blk&7 -> one XCD
    const int b   = bg >> 9;
    const int t   = threadIdx.x;

    const float* ctr = centers + (size_t)bg * 3;
    float cx = ctr[0], cy = ctr[1], cz = ctr[2];
    float cc2 = __fadd_rn(__fadd_rn(__fmul_rn(cx, cx), __fmul_rn(cy, cy)),
                          __fmul_rn(cz, cz));

    const float* PX = px + b * NN;
    const float* PY = py + b * NN;
    const float* PZ = pz + b * NN;

    float k1 = INFINITY, k2 = INFINITY;
    int   p1 = 0x7fffffff, p2 = 0x7fffffff;
    uint64_t mask = 0;   // consumed elements of my 64-pt chunk

#pragma unroll 4
    for (int i = 0; i < 64; ++i) {
        int pos = (i << 8) + t;           // coalesced
        float ax = PX[pos], ay = PY[pos], az = PZ[pos];
        float pp2 = __fadd_rn(__fadd_rn(__fmul_rn(ax, ax), __fmul_rn(ay, ay)),
                              __fmul_rn(az, az));
        float dot = fmaf(cz, az, fmaf(cy, ay, __fmul_rn(cx, ax)));
        float d2  = __fsub_rn(__fadd_rn(cc2, pp2), __fmul_rn(2.0f, dot));
        // ascending pos scan, strict '<': ties keep lower pos
        if (d2 < k1)      { k2 = k1; p2 = p1; k1 = d2; p1 = pos; }
        else if (d2 < k2) { k2 = d2; p2 = pos; }
    }

    __shared__ float s_v[2][4];
    __shared__ int   s_p[2][4];
    __shared__ int   s_chosen[KK];

    for (int j = 0; j < KK; ++j) {
        float v = k1; int vp = p1;
#pragma unroll
        for (int off = 32; off >= 1; off >>= 1) {
            float ov = __shfl_xor(v, off);
            int   op = __shfl_xor(vp, off);
            if (ov < v || (ov == v && op < vp)) { v = ov; vp = op; }
        }
        int par = j & 1;
        int w = t >> 6;
        if ((t & 63) == 0) { s_v[par][w] = v; s_p[par][w] = vp; }
        __syncthreads();
        // redundant scan of 4 partials by every thread
        float wv = s_v[par][0]; int wp = s_p[par][0];
#pragma unroll
        for (int q = 1; q < 4; ++q) {
            float qv = s_v[par][q]; int qp = s_p[par][q];
            if (qv < wv || (qv == wv && qp < wp)) { wv = qv; wp = qp; }
        }
        if (t == 0) s_chosen[j] = wp;
        if ((wp & 255) == t) {
            // I owned the extracted point: mark consumed, promote second
            mask |= 1ull << (wp >> 8);
            k1 = k2; p1 = p2;
            k2 = INFINITY; p2 = 0x7fffffff;
            if (p1 == 0x7fffffff && mask != 0xffffffffffffffffull) {
                // top-2 exhausted (rare): rebuild from unmasked points,
                // reloading coords from global; d2 bit-identical
                k1 = INFINITY;
#pragma unroll 1
                for (int i = 0; i < 64; ++i) {
                    if ((mask >> i) & 1ull) continue;
                    int pos = (i << 8) + t;
                    float ax = PX[pos], ay = PY[pos], az = PZ[pos];
                    float pp2 = __fadd_rn(__fadd_rn(__fmul_rn(ax, ax), __fmul_rn(ay, ay)),
                                          __fmul_rn(az, az));
                    float dot = fmaf(cz, az, fmaf(cy, ay, __fmul_rn(cx, ax)));
                    float d2  = __fsub_rn(__fadd_rn(cc2, pp2), __fmul_rn(2.0f, dot));
                    if (d2 < k1)      { k2 = k1; p2 = p1; k1 = d2; p1 = pos; }
                    else if (d2 < k2) { k2 = d2; p2 = pos; }
                }
            }
        }
        // no second barrier: parity buffer isolates next round's writes
    }
    __syncthreads();   // s_chosen visibility for gather

    // gather: 32 neighbors x 13 channels; subtract center from ch 4..6
    for (int v = t; v < KK * CC; v += 256) {
        int j = v / CC, c = v - j * CC;
        int pt = s_chosen[j] & (NN - 1);   // safety clamp (no-op when correct)
        float val = x[((size_t)b * NN + pt) * CC + c];
        if (c >= 4 && c < 7) {
            float cs = (c == 4) ? cx : ((c == 5) ? cy : cz);
            val = __fsub_rn(val, cs);
        }
        out[((size_t)bg * KK + j) * CC + c] = val;
    }
}

extern "C" void kernel_launch(void* const* d_in, const int* in_sizes, int n_in,
                              void* d_out, int out_size, void* d_ws, size_t ws_size,
                              hipStream_t stream) {
    const float* x = (const float*)d_in[0];
    float* out = (float*)d_out;
    float* centers = out + NEIGH_ELEMS;   // output 1 follows output 0, flat

    float* px = (float*)d_ws;
    float* py = px + BB * NN;
    float* pz = py + BB * NN;
    unsigned long long* key = (unsigned long long*)(pz + BB * NN); // 8-byte aligned
    unsigned int* cnt = (unsigned int*)(key + BB * GG);

    pack_kernel<<<(BB * NN + 255) / 256, 256, 0, stream>>>(x, px, py, pz);
    init_sync_kernel<<<(BB * GG + 255) / 256, 256, 0, stream>>>(key, cnt);
    fps_kernel<<<BB * SHARDS, FPS_THREADS, 0, stream>>>(px, py, pz, centers, key, cnt);
    knn_kernel<<<BB * GG, 256, 0, stream>>>(px, py, pz, x, centers, out);
}

// Round 13
// 4207.563 us; speedup vs baseline: 1.9348x; 1.9348x over previous
//
#include <hip/hip_runtime.h>
#include <stdint.h>
#include <math.h>

#define BB 8
#define NN 16384
#define CC 13
#define GG 512
#define KK 32

#define NEIGH_ELEMS (BB*GG*KK*CC)   // 1,703,936

#define SHARDS 8
#define SHARD_PTS (NN / SHARDS)        // 2048
#define FPS_THREADS 512
#define PPT (SHARD_PTS / FPS_THREADS)  // 4 points per thread

// ---------------------------------------------------------------------------
// Pack: x[B,N,13] (fp32) -> f32 SoA planes px,py,pz (channels 4..6).
// ---------------------------------------------------------------------------
__global__ void pack_kernel(const float* __restrict__ x,
                            float* __restrict__ px, float* __restrict__ py,
                            float* __restrict__ pz) {
    int i = blockIdx.x * blockDim.x + threadIdx.x;
    if (i >= BB * NN) return;
    const float* p = x + (size_t)i * CC + 4;
    px[i] = p[0]; py[i] = p[1]; pz[i] = p[2];
}

// ---------------------------------------------------------------------------
// Zero the per-(batch,step,shard) key slots. MUST run before fps every
// launch: harness poisons d_ws with 0xAA which would pre-satisfy the poll.
// ---------------------------------------------------------------------------
__global__ void init_sync_kernel(unsigned long long* __restrict__ key) {
    int i = blockIdx.x * blockDim.x + threadIdx.x;
    if (i < BB * GG * SHARDS) key[i] = 0ull;
}

// ---------------------------------------------------------------------------
// FPS v8 — sharded, low-contention handshake. 8 blocks/batch (64 total),
// 2048 pts each (4/thread, ~40 VGPRs, cannot spill).
// Per step: shard argmax (butterfly + 8 LDS partials), then t==0 only:
//   publish: plain float4 coord store -> release-store of packed key
//            (bits(bv)<<32 | 0xFFFFFFFF-idx); no atomic RMW, own slot.
//   wait:    poll the 8 slot keys (acquire) until all nonzero, take max
//            locally (keys unique -> deterministic, exact argmax+lowest-idx
//            tie semantics), read winner coords from that slot, LDS-bcast.
// R12 post-mortem: 32768 threads spinning on ONE counter line saturated L2
// (15.7us/step); now 64 waiters x 8 independent 8B loads per poll.
// Distance math verbatim from R6 (bit-exact vs golden).
// ---------------------------------------------------------------------------
__global__ __launch_bounds__(FPS_THREADS)
void fps_kernel(const float* __restrict__ px,
                const float* __restrict__ py,
                const float* __restrict__ pz,
                float* __restrict__ centers,
                unsigned long long* __restrict__ key,
                float4* __restrict__ crd) {
    const int b = blockIdx.x & 7;        // batch (shards of b share an XCD)
    const int s = blockIdx.x >> 3;       // shard id
    const int t = threadIdx.x;
    const float* PX = px + b * NN;
    const float* PY = py + b * NN;
    const float* PZ = pz + b * NN;
    unsigned long long* KEY = key + (size_t)b * GG * SHARDS;
    float4*             CRD = crd + (size_t)b * GG * SHARDS;

    const int base = s * SHARD_PTS + t;  // + i*512
    float X[PPT], Y[PPT], Z[PPT], MD[PPT];
#pragma unroll
    for (int i = 0; i < PPT; ++i) {
        int pos = base + (i << 9);
        X[i] = PX[pos]; Y[i] = PY[pos]; Z[i] = PZ[pos];
        MD[i] = 1e10f;   // init_d = 10000000000.0
    }

    __shared__ float s_v[8];
    __shared__ int   s_p[8];
    __shared__ float s_wx, s_wy, s_wz;

    if (s == 0 && t == 0) {
        float* oc = centers + (size_t)b * GG * 3;
        oc[0] = PX[0]; oc[1] = PY[0]; oc[2] = PZ[0];
    }
    float lx = PX[0], ly = PY[0], lz = PZ[0];

    for (int g = 1; g < GG; ++g) {
        float bv = -1.0f;
        int bp = 0x7fffffff;
#pragma unroll
        for (int i = 0; i < PPT; ++i) {
            float e0 = __fsub_rn(X[i], lx);
            float e1 = __fsub_rn(Y[i], ly);
            float e2 = __fsub_rn(Z[i], lz);
            float d  = __fadd_rn(__fadd_rn(__fmul_rn(e0, e0), __fmul_rn(e1, e1)),
                                 __fmul_rn(e2, e2));
            float m = fminf(MD[i], d);   // np.minimum
            MD[i] = m;
            // ascending-index scan + strict '>' keeps lowest index on ties
            if (m > bv) { bv = m; bp = base + (i << 9); }
        }
        // wave(64) butterfly argmax, tie -> lower index; carry coords? no:
        // winner coords come from the slot (bit-copies of PX/PY/PZ).
        float cxv = X[0], cyv = Y[0], czv = Z[0];
        // track coords of local best for publishing (cheap: PPT=4)
        {
            // recompute which i won to fetch coords without dynamic indexing
#pragma unroll
            for (int i = 0; i < PPT; ++i) {
                int pos = base + (i << 9);
                if (pos == bp) { cxv = X[i]; cyv = Y[i]; czv = Z[i]; }
            }
        }
#pragma unroll
        for (int off = 32; off >= 1; off >>= 1) {
            float ov = __shfl_xor(bv, off);
            int   op = __shfl_xor(bp, off);
            float ox = __shfl_xor(cxv, off);
            float oy = __shfl_xor(cyv, off);
            float oz = __shfl_xor(czv, off);
            if (ov > bv || (ov == bv && op < bp)) {
                bv = ov; bp = op; cxv = ox; cyv = oy; czv = oz;
            }
        }
        int w = t >> 6;
        if ((t & 63) == 0) { s_v[w] = bv; s_p[w] = bp; }
        __syncthreads();
        if (t == 0) {
            // scan 8 wave partials; need winner coords -> keep via index match
            float wv = s_v[0]; int wi = s_p[0];
#pragma unroll
            for (int q = 1; q < 8; ++q) {
                float qv = s_v[q]; int qp = s_p[q];
                if (qv > wv || (qv == wv && qp < wi)) { wv = qv; wi = qp; }
            }
            // fetch shard-winner coords: if my wave won use carried regs,
            // else scalar load (uniform index, off critical path of others)
            float sx, sy, sz;
            if (wi == bp) { sx = cxv; sy = cyv; sz = czv; }
            else          { sx = PX[wi]; sy = PY[wi]; sz = PZ[wi]; }
            // publish: coords first (plain), then key with RELEASE
            size_t slot = (size_t)g * SHARDS + s;
            CRD[slot] = make_float4(sx, sy, sz, 0.0f);
            unsigned long long k =
                ((unsigned long long)__float_as_uint(wv) << 32) |
                (unsigned long long)(0xFFFFFFFFu - (unsigned int)wi);
            __hip_atomic_store(&KEY[slot], k, __ATOMIC_RELEASE,
                               __HIP_MEMORY_SCOPE_AGENT);
            // wait for all 8 shards (8 independent 8B acquire loads/pass)
            unsigned long long kk[SHARDS];
            bool ready = false;
            while (!ready) {
                ready = true;
#pragma unroll
                for (int q = 0; q < SHARDS; ++q) {
                    kk[q] = __hip_atomic_load(&KEY[(size_t)g * SHARDS + q],
                                              __ATOMIC_ACQUIRE,
                                              __HIP_MEMORY_SCOPE_AGENT);
                    if (kk[q] == 0ull) ready = false;
                }
            }
            unsigned long long best = kk[0]; int bs = 0;
#pragma unroll
            for (int q = 1; q < SHARDS; ++q)
                if (kk[q] > best) { best = kk[q]; bs = q; }
            float4 wc = CRD[(size_t)g * SHARDS + bs];  // ordered by acquire
            s_wx = wc.x; s_wy = wc.y; s_wz = wc.z;
            if (s == 0) {
                float* oc = centers + ((size_t)b * GG + g) * 3;
                oc[0] = wc.x; oc[1] = wc.y; oc[2] = wc.z;
            }
        }
        __syncthreads();
        lx = s_wx; ly = s_wy; lz = s_wz;
    }
}

// ---------------------------------------------------------------------------
// KNN v2 + gather (unchanged from R8): one 256-thread block per center,
// 64 pts/thread, top-2 cache + rare global rescan; XCD swizzle keeps each
// batch's SoA L2-resident on one XCD. d2 math bit-exact vs golden.
// ---------------------------------------------------------------------------
__global__ __launch_bounds__(256, 8) void knn_kernel(const float* __restrict__ px,
                                                     const float* __restrict__ py,
                                                     const float* __restrict__ pz,
                                                     const float* __restrict__ x,
                                                     const float* __restrict__ centers,
                                                     float* __restrict__ out) {
    const int blk = blockIdx.x;
    const int bg  = ((blk & 7) << 9) | (blk >> 3);   // batch = blk&7 -> one XCD
    const int b   = bg >> 9;
    const int t   = threadIdx.x;

    const float* ctr = centers + (size_t)bg * 3;
    float cx = ctr[0], cy = ctr[1], cz = ctr[2];
    float cc2 = __fadd_rn(__fadd_rn(__fmul_rn(cx, cx), __fmul_rn(cy, cy)),
                          __fmul_rn(cz, cz));

    const float* PX = px + b * NN;
    const float* PY = py + b * NN;
    const float* PZ = pz + b * NN;

    float k1 = INFINITY, k2 = INFINITY;
    int   p1 = 0x7fffffff, p2 = 0x7fffffff;
    uint64_t mask = 0;   // consumed elements of my 64-pt chunk

#pragma unroll 4
    for (int i = 0; i < 64; ++i) {
        int pos = (i << 8) + t;           // coalesced
        float ax = PX[pos], ay = PY[pos], az = PZ[pos];
        float pp2 = __fadd_rn(__fadd_rn(__fmul_rn(ax, ax), __fmul_rn(ay, ay)),
                              __fmul_rn(az, az));
        float dot = fmaf(cz, az, fmaf(cy, ay, __fmul_rn(cx, ax)));
        float d2  = __fsub_rn(__fadd_rn(cc2, pp2), __fmul_rn(2.0f, dot));
        // ascending pos scan, strict '<': ties keep lower pos
        if (d2 < k1)      { k2 = k1; p2 = p1; k1 = d2; p1 = pos; }
        else if (d2 < k2) { k2 = d2; p2 = pos; }
    }

    __shared__ float s_v[2][4];
    __shared__ int   s_p[2][4];
    __shared__ int   s_chosen[KK];

    for (int j = 0; j < KK; ++j) {
        float v = k1; int vp = p1;
#pragma unroll
        for (int off = 32; off >= 1; off >>= 1) {
            float ov = __shfl_xor(v, off);
            int   op = __shfl_xor(vp, off);
            if (ov < v || (ov == v && op < vp)) { v = ov; vp = op; }
        }
        int par = j & 1;
        int w = t >> 6;
        if ((t & 63) == 0) { s_v[par][w] = v; s_p[par][w] = vp; }
        __syncthreads();
        // redundant scan of 4 partials by every thread
        float wv = s_v[par][0]; int wp = s_p[par][0];
#pragma unroll
        for (int q = 1; q < 4; ++q) {
            float qv = s_v[par][q]; int qp = s_p[par][q];
            if (qv < wv || (qv == wv && qp < wp)) { wv = qv; wp = qp; }
        }
        if (t == 0) s_chosen[j] = wp;
        if ((wp & 255) == t) {
            // I owned the extracted point: mark consumed, promote second
            mask |= 1ull << (wp >> 8);
            k1 = k2; p1 = p2;
            k2 = INFINITY; p2 = 0x7fffffff;
            if (p1 == 0x7fffffff && mask != 0xffffffffffffffffull) {
                // top-2 exhausted (rare): rebuild from unmasked points,
                // reloading coords from global; d2 bit-identical
                k1 = INFINITY;
#pragma unroll 1
                for (int i = 0; i < 64; ++i) {
                    if ((mask >> i) & 1ull) continue;
                    int pos = (i << 8) + t;
                    float ax = PX[pos], ay = PY[pos], az = PZ[pos];
                    float pp2 = __fadd_rn(__fadd_rn(__fmul_rn(ax, ax), __fmul_rn(ay, ay)),
                                          __fmul_rn(az, az));
                    float dot = fmaf(cz, az, fmaf(cy, ay, __fmul_rn(cx, ax)));
                    float d2  = __fsub_rn(__fadd_rn(cc2, pp2), __fmul_rn(2.0f, dot));
                    if (d2 < k1)      { k2 = k1; p2 = p1; k1 = d2; p1 = pos; }
                    else if (d2 < k2) { k2 = d2; p2 = pos; }
                }
            }
        }
        // no second barrier: parity buffer isolates next round's writes
    }
    __syncthreads();   // s_chosen visibility for gather

    // gather: 32 neighbors x 13 channels; subtract center from ch 4..6
    for (int v = t; v < KK * CC; v += 256) {
        int j = v / CC, c = v - j * CC;
        int pt = s_chosen[j] & (NN - 1);   // safety clamp (no-op when correct)
        float val = x[((size_t)b * NN + pt) * CC + c];
        if (c >= 4 && c < 7) {
            float cs = (c == 4) ? cx : ((c == 5) ? cy : cz);
            val = __fsub_rn(val, cs);
        }
        out[((size_t)bg * KK + j) * CC + c] = val;
    }
}

extern "C" void kernel_launch(void* const* d_in, const int* in_sizes, int n_in,
                              void* d_out, int out_size, void* d_ws, size_t ws_size,
                              hipStream_t stream) {
    const float* x = (const float*)d_in[0];
    float* out = (float*)d_out;
    float* centers = out + NEIGH_ELEMS;   // output 1 follows output 0, flat

    float* px = (float*)d_ws;
    float* py = px + BB * NN;
    float* pz = py + BB * NN;
    unsigned long long* key = (unsigned long long*)(pz + BB * NN); // 8B aligned
    float4* crd = (float4*)(key + (size_t)BB * GG * SHARDS);       // 16B aligned

    pack_kernel<<<(BB * NN + 255) / 256, 256, 0, stream>>>(x, px, py, pz);
    init_sync_kernel<<<(BB * GG * SHARDS + 255) / 256, 256, 0, stream>>>(key);
    fps_kernel<<<BB * SHARDS, FPS_THREADS, 0, stream>>>(px, py, pz, centers, key, crd);
    knn_kernel<<<BB * GG, 256, 0, stream>>>(px, py, pz, x, centers, out);
}